// Round 4
// baseline (983.934 us; speedup 1.0000x reference)
//
#include <hip/hip_runtime.h>

// Problem constants (from reference setup_inputs)
static constexpr int B = 4, C = 3, H = 1080, W = 1920;
static constexpr int HW = H * W;          // 2,073,600
static constexpr int NPIX = B * HW;       // 8,294,400
static constexpr int BLOCK = 256;

// Target-domain tiling. Tile 32x32 -> k_tile LDS = 4 KB (dmax) + 16 KB (acc)
// = 20 KB -> 8 WG/CU by LDS.
static constexpr int TW = 32, TH = 32;
static constexpr int TPX = TW * TH;              // 1024
static constexpr int TXN = W / TW;               // 60 (exact)
static constexpr int TYN = (H + TH - 1) / TH;    // 34 (last tile 24 rows)
static constexpr int NT = TXN * TYN;             // 2040 tiles per batch
static constexpr int CAP = 1536;                 // entries/bin; mean ~1085, sigma ~33
static constexpr int OFL_CAP = 65536;            // overflow list capacity

// k_bin: 4 pixels per thread -> 8100 blocks; histogram amortized 4x.
static constexpr int PPT = 4;
static constexpr int BPIX = BLOCK * PPT;         // 1024 pixels per block
static constexpr int BPB = HW / BPIX;            // 2025 blocks per batch (exact)

// Depth key must match numpy bit-exactly: no FMA contraction, round-half-even.
__device__ __forceinline__ int depth_key(float fx, float fy) {
    float m2 = __fadd_rn(__fmul_rn(fx, fx), __fmul_rn(fy, fy));
    return (int)rintf(__fmul_rn(sqrtf(m2), 1000.0f));
}

// Overflow-path fallback: merge this pixel's full footprint into global dbuf.
__device__ __forceinline__ void merge_depth(int* __restrict__ dbuf, int bHW,
                                            float x, float y, int d) {
    int x0 = (int)floorf(x), y0 = (int)floorf(y);
    #pragma unroll
    for (int yy = 0; yy < 2; ++yy) {
        int cy = y0 + yy;
        if ((unsigned)cy >= (unsigned)H) continue;
        #pragma unroll
        for (int xx = 0; xx < 2; ++xx) {
            int cx = x0 + xx;
            if ((unsigned)cx >= (unsigned)W) continue;
            atomicMax(&dbuf[bHW + cy * W + cx], d);
        }
    }
}

// ---------------------------------------------------------------------------
// Pass 1: bin every source pixel into the tile(s) its 2x2 corner footprint
// touches (~1.06 avg). Per-block LDS histogram -> one global atomic per
// unique tile per block. 16-B entries {x,y,pix,d}. Branchless phase 1.
__global__ __launch_bounds__(BLOCK) void k_bin(const float2* __restrict__ flow,
                                               int* __restrict__ cnt,
                                               float4* __restrict__ bin,
                                               int* __restrict__ ofl_cnt,
                                               int* __restrict__ ofl_i,
                                               int* __restrict__ ofl_t,
                                               int* __restrict__ dbuf) {
    __shared__ int hcnt[NT];    // per-block per-tile count
    __shared__ int hbase[NT];   // global base slot for this block
    const int tid = threadIdx.x;
    const int b = blockIdx.x / BPB;              // block never straddles batches
    const int gbase = blockIdx.x * BPIX + tid;

    // Issue all flow loads BEFORE the LDS init loop so their latency hides.
    float2 f[PPT];
    #pragma unroll
    for (int k = 0; k < PPT; ++k) f[k] = flow[gbase + k * BLOCK];

    for (int j = tid; j < NT; j += BLOCK) hcnt[j] = 0;
    __syncthreads();

    // Phase 1: corner tiles (static dedup, -1 = absent) + branchless rank
    // grab: invalid corners add 0 to slot 0 (harmless, no divergence).
    float xs[PPT], ys[PPT];
    int dd[PPT];
    int ta[PPT], tb[PPT], tc[PPT], td[PPT];
    int ra[PPT], rb[PPT], rc[PPT], rd[PPT];
    #pragma unroll
    for (int k = 0; k < PPT; ++k) {
        const int i = gbase + k * BLOCK;
        const int pix = i - b * HW;
        const int h = pix / W;
        const int w = pix - h * W;
        const float x = (float)w + f[k].x;
        const float y = (float)h + f[k].y;
        xs[k] = x; ys[k] = y;
        dd[k] = depth_key(f[k].x, f[k].y);
        const int x0 = (int)floorf(x), y0 = (int)floorf(y);
        const int x1 = x0 + 1, y1 = y0 + 1;
        const bool vx0 = (unsigned)x0 < (unsigned)W, vx1 = (unsigned)x1 < (unsigned)W;
        const bool vy0 = (unsigned)y0 < (unsigned)H, vy1 = (unsigned)y1 < (unsigned)H;
        const int cx0 = x0 >> 5, cx1 = x1 >> 5;
        const int cy0 = y0 >> 5, cy1 = y1 >> 5;
        const bool dupx = (cx1 == cx0), dupy = (cy1 == cy0);
        ta[k] = (vy0 && vx0)                   ? cy0 * TXN + cx0 : -1;
        tb[k] = (vy0 && vx1 && !dupx)          ? cy0 * TXN + cx1 : -1;
        tc[k] = (vy1 && vx0 && !dupy)          ? cy1 * TXN + cx0 : -1;
        td[k] = (vy1 && vx1 && !dupx && !dupy) ? cy1 * TXN + cx1 : -1;
        ra[k] = atomicAdd(&hcnt[ta[k] < 0 ? 0 : ta[k]], ta[k] < 0 ? 0 : 1);
        rb[k] = atomicAdd(&hcnt[tb[k] < 0 ? 0 : tb[k]], tb[k] < 0 ? 0 : 1);
        rc[k] = atomicAdd(&hcnt[tc[k] < 0 ? 0 : tc[k]], tc[k] < 0 ? 0 : 1);
        rd[k] = atomicAdd(&hcnt[td[k] < 0 ? 0 : td[k]], td[k] < 0 ? 0 : 1);
    }
    __syncthreads();

    // Phase 2: one global atomic per touched tile, grab base slots.
    for (int j = tid; j < NT; j += BLOCK) {
        int c = hcnt[j];
        if (c > 0) hbase[j] = atomicAdd(&cnt[b * NT + j], c);
    }
    __syncthreads();

    // Phase 3: write fat entries {x,y,pix,d} at base+rank (clustered stores).
    // Overflow (never expected): depth merged into dbuf once per pixel,
    // accumulation deferred to the list.
    #pragma unroll
    for (int k = 0; k < PPT; ++k) {
        const int i = gbase + k * BLOCK;
        const int pix = i - b * HW;
        const float4 entry = make_float4(xs[k], ys[k],
                                         __int_as_float(pix), __int_as_float(dd[k]));
        bool fb = false;
        #define EMIT(T, R)                                                     \
            if ((T) >= 0) {                                                    \
                int slot = hbase[T] + (R);                                     \
                if (slot < CAP) {                                              \
                    bin[(size_t)(b * NT + (T)) * CAP + slot] = entry;          \
                } else {                                                       \
                    int pos = atomicAdd(ofl_cnt, 1);                           \
                    if (pos < OFL_CAP) { ofl_i[pos] = i; ofl_t[pos] = (T); }   \
                    if (!fb) {                                                 \
                        fb = true;                                             \
                        merge_depth(dbuf, b * HW, xs[k], ys[k], dd[k]);        \
                    }                                                          \
                }                                                              \
            }
        EMIT(ta[k], ra[k])
        EMIT(tb[k], rb[k])
        EMIT(tc[k], rc[k])
        EMIT(td[k], rd[k])
        #undef EMIT
    }
}

// ---------------------------------------------------------------------------
// Pass 2: fused depth+accumulate per tile. Both scans are fully BRANCHLESS:
// tiles are 32-aligned so loc = ((cy&31)<<5)|(cx&31) is always a valid slot
// (wraps harmlessly for out-of-tile corners); out-of-tile / losing corners
// contribute atomicMax(-1) / atomicAdd(0), which are value-level no-ops.
// No exec-mask gymnastics anywhere in the hot loops.
__global__ __launch_bounds__(BLOCK) void k_tile(const float* __restrict__ im0,
                                                const int* __restrict__ cnt,
                                                const float4* __restrict__ bin,
                                                const int* __restrict__ ofl_cnt,
                                                int* __restrict__ dbuf,
                                                float* __restrict__ wght,
                                                float* __restrict__ out) {
    __shared__ int   dmax[TPX];       // 4 KB
    __shared__ float acc0[TPX];       // 4 plane arrays: each atomic instr
    __shared__ float acc1[TPX];       // spreads lanes over all 32 banks
    __shared__ float acc2[TPX];
    __shared__ float acc3[TPX];
    const int tid = threadIdx.x;
    const int bx = blockIdx.x, by = blockIdx.y, b = blockIdx.z;
    const int tx0 = bx * TW, ty0 = by * TH;
    const int t = by * TXN + bx;
    const bool have_ofl = (*ofl_cnt) > 0;   // uniform, input-determined
    int* db = dbuf + (size_t)b * HW;

    for (int i = tid; i < TPX; i += BLOCK) {
        int gy = ty0 + (i >> 5), gx = tx0 + (i & 31);
        dmax[i] = (have_ofl && gy < H) ? db[gy * W + gx] : 0;
        acc0[i] = 0.0f; acc1[i] = 0.0f; acc2[i] = 0.0f; acc3[i] = 0.0f;
    }
    __syncthreads();

    const int n = min(cnt[b * NT + t], CAP);
    const float4* mybin = bin + (size_t)(b * NT + t) * CAP;

    // scan 1: depth max into LDS — 1 coalesced 16B load + 4 unconditional
    // LDS atomicMax per entry. Zero branches.
    for (int e = tid; e < n; e += BLOCK) {
        float4 a = mybin[e];
        int x0 = (int)floorf(a.x);
        int y0 = (int)floorf(a.y);
        int d = __float_as_int(a.w);
        #pragma unroll
        for (int dy = 0; dy < 2; ++dy) {
            #pragma unroll
            for (int dx = 0; dx < 2; ++dx) {
                int cx = x0 + dx, cy = y0 + dy;
                bool in = ((cx >> 5) == bx) & ((cy >> 5) == by) & (cy < H);
                int loc = ((cy & 31) << 5) | (cx & 31);
                atomicMax(&dmax[loc], in ? d : -1);
            }
        }
    }
    __syncthreads();

    // publish merged depth only when the overflow kernel will need it
    if (have_ofl) {
        for (int i = tid; i < TPX; i += BLOCK) {
            int gy = ty0 + (i >> 5), gx = tx0 + (i & 31);
            if (gy < H) db[gy * W + gx] = dmax[i];
        }
    }

    // scan 2: depth-tested accumulation. Colors gathered unconditionally
    // (issued right after the entry load -> deep MLP); losers add 0.
    const float* ib = im0 + (size_t)b * C * HW;
    for (int e = tid; e < n; e += BLOCK) {
        float4 a = mybin[e];
        int pix = __float_as_int(a.z);
        float c0 = ib[pix];
        float c1 = ib[pix + HW];
        float c2 = ib[pix + 2 * HW];
        float x0f = floorf(a.x), y0f = floorf(a.y);
        int x0 = (int)x0f, y0 = (int)y0f;
        int d = __float_as_int(a.w);
        float ax = __fsub_rn(a.x, x0f);
        float ay = __fsub_rn(a.y, y0f);
        float wx[2] = { __fsub_rn(1.0f, ax), ax };
        float wy[2] = { __fsub_rn(1.0f, ay), ay };
        #pragma unroll
        for (int dy = 0; dy < 2; ++dy) {
            #pragma unroll
            for (int dx = 0; dx < 2; ++dx) {
                int cx = x0 + dx, cy = y0 + dy;
                bool in = ((cx >> 5) == bx) & ((cy >> 5) == by) & (cy < H);
                int loc = ((cy & 31) << 5) | (cx & 31);
                int dm = dmax[loc];
                float wg = (in & (dm == d)) ? __fmul_rn(wx[dx], wy[dy]) : 0.0f;
                atomicAdd(&acc0[loc], wg);
                atomicAdd(&acc1[loc], __fmul_rn(c0, wg));
                atomicAdd(&acc2[loc], __fmul_rn(c1, wg));
                atomicAdd(&acc3[loc], __fmul_rn(c2, wg));
            }
        }
    }
    __syncthreads();

    float* ob = out + (size_t)b * C * HW;
    float* wb = wght + (size_t)b * HW;
    for (int i = tid; i < TPX; i += BLOCK) {
        int gy = ty0 + (i >> 5), gx = tx0 + (i & 31);
        if (gy >= H) continue;
        int g = gy * W + gx;
        float a0 = acc0[i], a1 = acc1[i], a2 = acc2[i], a3 = acc3[i];
        if (have_ofl) {  // overflow exists: store raw sums, norm pass finishes
            wb[g] = a0;
            ob[g] = a1; ob[g + HW] = a2; ob[g + 2 * HW] = a3;
        } else {         // common case: fused normalize
            float wv = fmaxf(a0, 1e-5f);
            ob[g]          = __fdiv_rn(a1, wv);
            ob[g + HW]     = __fdiv_rn(a2, wv);
            ob[g + 2 * HW] = __fdiv_rn(a3, wv);
        }
    }
}

// ---------------------------------------------------------------------------
// Overflow accumulation (normally zero work): global atomics, corners
// restricted to the overflowed tile (other tiles own their own copies).
__global__ __launch_bounds__(BLOCK) void k_accum_ofl(const float* __restrict__ im0,
                                                     const float2* __restrict__ flow,
                                                     const int* __restrict__ ofl_cnt,
                                                     const int* __restrict__ ofl_i,
                                                     const int* __restrict__ ofl_t,
                                                     const int* __restrict__ dbuf,
                                                     float* __restrict__ wght,
                                                     float* __restrict__ out) {
    int k = blockIdx.x * BLOCK + threadIdx.x;
    int n = min(*ofl_cnt, OFL_CAP);
    if (k >= n) return;
    int i = ofl_i[k], t = ofl_t[k];
    int b = i / HW;
    int pix = i - b * HW;
    int h = pix / W, w = pix - h * W;
    int bx = t % TXN, by = t / TXN;
    float2 f = flow[i];
    float x = (float)w + f.x;
    float y = (float)h + f.y;
    float x0f = floorf(x), y0f = floorf(y);
    int x0 = (int)x0f, y0 = (int)y0f;
    float ax = __fsub_rn(x, x0f);
    float ay = __fsub_rn(y, y0f);
    int d = depth_key(f.x, f.y);
    const float* src = im0 + (size_t)b * C * HW + pix;
    float c0 = src[0], c1 = src[HW], c2 = src[2 * HW];
    float wxv[2] = { __fsub_rn(1.0f, ax), ax };
    float wyv[2] = { __fsub_rn(1.0f, ay), ay };
    #pragma unroll
    for (int dy = 0; dy < 2; ++dy) {
        int cy = y0 + dy;
        if ((cy >> 5) != by || cy >= H) continue;
        #pragma unroll
        for (int dx = 0; dx < 2; ++dx) {
            int cx = x0 + dx;
            if ((cx >> 5) != bx) continue;
            int idx = b * HW + cy * W + cx;
            if (dbuf[idx] != d) continue;
            float wg = __fmul_rn(wxv[dx], wyv[dy]);
            atomicAdd(&wght[idx], wg);
            float* o = out + (size_t)b * C * HW + cy * W + cx;
            atomicAdd(&o[0],      __fmul_rn(c0, wg));
            atomicAdd(&o[HW],     __fmul_rn(c1, wg));
            atomicAdd(&o[2 * HW], __fmul_rn(c2, wg));
        }
    }
}

// Norm pass: only active when overflow occurred (k_tile stored raw sums).
__global__ __launch_bounds__(BLOCK) void k_norm(float* __restrict__ out,
                                                const float* __restrict__ wght,
                                                const int* __restrict__ ofl_cnt) {
    if (*ofl_cnt == 0) return;
    for (int i = blockIdx.x * BLOCK + threadIdx.x; i < NPIX;
         i += gridDim.x * BLOCK) {
        int b = i / HW;
        int pix = i - b * HW;
        float wv = fmaxf(wght[i], 1e-5f);
        float* o = out + (size_t)b * C * HW + pix;
        o[0]      = __fdiv_rn(o[0], wv);
        o[HW]     = __fdiv_rn(o[HW], wv);
        o[2 * HW] = __fdiv_rn(o[2 * HW], wv);
    }
}

extern "C" void kernel_launch(void* const* d_in, const int* in_sizes, int n_in,
                              void* d_out, int out_size, void* d_ws, size_t ws_size,
                              hipStream_t stream) {
    const float*  im0  = (const float*)d_in[0];   // [B,C,H,W]
    const float2* flow = (const float2*)d_in[1];  // [B,H,W,2] as float2
    float* out = (float*)d_out;                   // [B,C,H,W]

    // Workspace layout (bytes): bin first (16B-aligned), then scalars.
    // Total 267.5 MB (proven in rounds 1-2).
    char* ws = (char*)d_ws;
    float4* bin = (float4*)ws;                                      // B*NT*CAP*16 (~200 MB)
    const size_t bin_bytes = (size_t)B * NT * CAP * sizeof(float4);
    int*   dbuf    = (int*)(ws + bin_bytes);                        // NPIX
    float* wght    = (float*)(ws + bin_bytes + (size_t)NPIX * 4);   // NPIX
    int*   cnt     = (int*)(ws + bin_bytes + (size_t)NPIX * 8);     // B*NT
    int*   ofl_cnt = cnt + B * NT;                                  // 1 (adjacent to cnt)
    int*   ofl_i   = ofl_cnt + 1;                                   // OFL_CAP
    int*   ofl_t   = ofl_i + OFL_CAP;                               // OFL_CAP

    hipMemsetAsync(dbuf, 0, (size_t)NPIX * 4, stream);
    hipMemsetAsync(cnt, 0, (size_t)(B * NT + 1) * 4, stream);

    int bgrid = NPIX / BPIX;    // 8100
    dim3 tgrid(TXN, TYN, B);    // 60 x 34 x 4 = 8160 tiles

    k_bin      <<<bgrid, BLOCK, 0, stream>>>(flow, cnt, bin, ofl_cnt, ofl_i, ofl_t, dbuf);
    k_tile     <<<tgrid, BLOCK, 0, stream>>>(im0, cnt, bin, ofl_cnt, dbuf, wght, out);
    k_accum_ofl<<<OFL_CAP / BLOCK, BLOCK, 0, stream>>>(im0, flow, ofl_cnt, ofl_i, ofl_t, dbuf, wght, out);
    k_norm     <<<2048, BLOCK, 0, stream>>>(out, wght, ofl_cnt);
}